// Round 1
// 367.098 us; speedup vs baseline: 1.1143x; 1.1143x over previous
//
#include <hip/hip_runtime.h>

typedef __bf16 bf16_t;
typedef __bf16 bf16x2 __attribute__((ext_vector_type(2)));
typedef __bf16 bf16x8 __attribute__((ext_vector_type(8)));
typedef float floatx4 __attribute__((ext_vector_type(4)));

#define B_ 4
#define S_ 4096
#define D_ 1024
#define H_ 16
#define HD_ 64
#define M_TOT (B_ * S_)   // 16384

__device__ __forceinline__ void async_load16(const bf16_t* g, bf16_t* l) {
  __builtin_amdgcn_global_load_lds(
      (const __attribute__((address_space(1))) void*)g,
      (__attribute__((address_space(3))) void*)l,
      16, 0, 0);
}

// ---------------- fused prep: casts + weight transposes ----------------
//   [0,8192)      : cast query fp32 -> Aq bf16
//   [8192,16384)  : cast key_value fp32 -> Akv bf16
//   [16384,20480) : 4x transpose-cast W (KxN fp32) -> Wt (NxK bf16)
struct PrepArgs {
  const float* q; const float* kv;
  bf16_t* aq; bf16_t* akv;
  const float* w0; const float* w1; const float* w2; const float* w3;
  bf16_t* t0; bf16_t* t1; bf16_t* t2; bf16_t* t3;
};

__global__ __launch_bounds__(256) void prep_kernel(PrepArgs p) {
  __shared__ float tile[32][33];
  const int bid = blockIdx.x;
  const int t = threadIdx.x;
  if (bid < 16384) {
    const float* in = bid < 8192 ? p.q : p.kv;
    bf16_t* out = bid < 8192 ? p.aq : p.akv;
    int i = ((bid & 8191) * 256 + t) * 8;
    float4 a = *(const float4*)(in + i);
    float4 b = *(const float4*)(in + i + 4);
    bf16x8 o;
    o[0] = (bf16_t)a.x; o[1] = (bf16_t)a.y; o[2] = (bf16_t)a.z; o[3] = (bf16_t)a.w;
    o[4] = (bf16_t)b.x; o[5] = (bf16_t)b.y; o[6] = (bf16_t)b.z; o[7] = (bf16_t)b.w;
    *(bf16x8*)(out + i) = o;
  } else {
    int idx = bid - 16384;
    int z = idx >> 10;
    int rem = idx & 1023;
    const float* W = z == 0 ? p.w0 : z == 1 ? p.w1 : z == 2 ? p.w2 : p.w3;
    bf16_t* Wt = z == 0 ? p.t0 : z == 1 ? p.t1 : z == 2 ? p.t2 : p.t3;
    int n0 = (rem & 31) * 32;
    int k0 = (rem >> 5) * 32;
    int tx = t & 31;
    int ty = t >> 5;  // 0..7
    for (int r = ty; r < 32; r += 8)
      tile[r][tx] = W[(size_t)(k0 + r) * D_ + n0 + tx];
    __syncthreads();
    for (int r = ty; r < 32; r += 8)
      Wt[(size_t)(n0 + r) * D_ + k0 + tx] = (bf16_t)tile[tx][r];
  }
}

// ---------------- 256x256 GEMM core: BK=32, ring-4 LDS, counted vmcnt ----------------
// 512 threads = 8 waves (2 M-groups x 4 N-groups). Per wave: 128x64 output,
// acc[8][4] 16x16 fragments. One raw s_barrier per K-tile; vmcnt(8) keeps
// 2 K-tiles of global_load_lds in flight across the barrier (T3/T4).
// LDS chunk swizzle: phys chunk q = logical lq ^ ((row>>1)&3), pre-applied to
// the GLOBAL source address so global_load_lds dest stays linear (rule #21).
__device__ __forceinline__ void gemm256_core(
    const bf16_t* __restrict__ A, const bf16_t* __restrict__ Bt,
    int row0, int col0, bf16_t* As, bf16_t* Bs, floatx4 (&acc)[8][4]) {
  const int tid = threadIdx.x;
  const int w = tid >> 6;
  const int lane = tid & 63;
  const int lr = lane & 15;
  const int lq = lane >> 4;
  const int wm0 = (w >> 2) * 128;
  const int wn0 = (w & 3) * 64;

  // staging: thread covers chunks c0 (rows 0..127) and c1 (rows 128..255)
  const int c0 = w * 64 + lane;
  const int c1 = c0 + 512;
  const int r0 = c0 >> 2, q0 = c0 & 3;
  const int r1 = c1 >> 2, q1 = c1 & 3;
  const size_t offA0 = (size_t)(row0 + r0) * D_ + ((q0 ^ ((r0 >> 1) & 3)) * 8);
  const size_t offA1 = (size_t)(row0 + r1) * D_ + ((q1 ^ ((r1 >> 1) & 3)) * 8);
  const size_t offB0 = (size_t)(col0 + r0) * D_ + ((q0 ^ ((r0 >> 1) & 3)) * 8);
  const size_t offB1 = (size_t)(col0 + r1) * D_ + ((q1 ^ ((r1 >> 1) & 3)) * 8);
  const int ldst0 = w * 512;          // elems; HW adds lane*16B
  const int ldst1 = 4096 + w * 512;
  const int swz = (lq ^ ((lr >> 1) & 3)) * 8;  // read-side swizzle (elems)

#define STAGE_TILE(tt)                                   \
  {                                                      \
    bf16_t* as_ = As + ((tt) & 3) * 8192;                \
    bf16_t* bs_ = Bs + ((tt) & 3) * 8192;                \
    const int ko_ = (tt) * 32;                           \
    async_load16(A + offA0 + ko_, as_ + ldst0);          \
    async_load16(A + offA1 + ko_, as_ + ldst1);          \
    async_load16(Bt + offB0 + ko_, bs_ + ldst0);         \
    async_load16(Bt + offB1 + ko_, bs_ + ldst1);         \
  }

  STAGE_TILE(0)
  STAGE_TILE(1)

  for (int kt = 0; kt < 32; ++kt) {
    if (kt < 30) {
      STAGE_TILE(kt + 2)
      // counted wait: tile kt landed, tiles kt+1/kt+2 (8 loads) stay in flight
      asm volatile("s_waitcnt vmcnt(8)\n\ts_barrier" ::: "memory");
    } else if (kt == 30) {
      asm volatile("s_waitcnt vmcnt(4)\n\ts_barrier" ::: "memory");
    } else {
      asm volatile("s_waitcnt vmcnt(0)\n\ts_barrier" ::: "memory");
    }
    const bf16_t* as = As + (kt & 3) * 8192;
    const bf16_t* bs = Bs + (kt & 3) * 8192;
    bf16x8 af[8], bfr[4];
#pragma unroll
    for (int i = 0; i < 8; ++i)
      af[i] = *(const bf16x8*)&as[(wm0 + i * 16 + lr) * 32 + swz];
#pragma unroll
    for (int j = 0; j < 4; ++j)
      bfr[j] = *(const bf16x8*)&bs[(wn0 + j * 16 + lr) * 32 + swz];
    __builtin_amdgcn_s_setprio(1);
#pragma unroll
    for (int i = 0; i < 8; ++i)
#pragma unroll
      for (int j = 0; j < 4; ++j)
        acc[i][j] = __builtin_amdgcn_mfma_f32_16x16x32_bf16(af[i], bfr[j], acc[i][j], 0, 0, 0);
    __builtin_amdgcn_s_setprio(0);
  }
#undef STAGE_TILE
}

// ---------------- merged Q/K/V projection (256^2 tiles) ----------------
// grid 768: per XCD 96 slots; 24-slot supertiles = 2 mt x 12 nt for L2 reuse.
// nt<4: C=Aq*WqT (elu+1 -> Qf). nt in 4..7: Akv*Wk' (elu+1 -> Kf). nt>=8: Akv*Wv' (bias -> Vf).
struct ProjArgs {
  const bf16_t* Aq; const bf16_t* Akv;
  const bf16_t* WqT; const bf16_t* WkvT;  // WkvT = 2048 x 1024 (Wk rows then Wv rows)
  const float* bq; const float* bk; const float* bv;
  bf16_t* Qf; bf16_t* Kf; bf16_t* Vf;
};

__global__ __launch_bounds__(512, 2) void proj256_kernel(ProjArgs p) {
  __shared__ __attribute__((aligned(16))) bf16_t As[4 * 8192];  // 64KB
  __shared__ __attribute__((aligned(16))) bf16_t Bs[4 * 8192];  // 64KB
  const unsigned L = blockIdx.x;
  const unsigned xcd = L & 7;
  const unsigned slot = L >> 3;        // 0..95
  const unsigned mq = slot / 24u;      // 0..3
  const unsigned s24 = slot % 24u;
  const int mt = xcd * 8 + mq * 2 + (s24 & 1);   // 0..63
  const int nt = s24 >> 1;                        // 0..11
  const bool isQ = nt < 4;
  const int row0 = mt * 256;
  const int col0 = (isQ ? nt : nt - 4) * 256;
  const bf16_t* A = isQ ? p.Aq : p.Akv;
  const bf16_t* Bt = isQ ? p.WqT : p.WkvT;

  floatx4 acc[8][4];
#pragma unroll
  for (int i = 0; i < 8; ++i)
#pragma unroll
    for (int j = 0; j < 4; ++j) acc[i][j] = (floatx4){0.f, 0.f, 0.f, 0.f};

  gemm256_core(A, Bt, row0, col0, As, Bs, acc);

  const int tid = threadIdx.x;
  const int w = tid >> 6;
  const int lane = tid & 63;
  const int lr = lane & 15;
  const int lq = lane >> 4;
  const int wm0 = (w >> 2) * 128;
  const int wn0 = (w & 3) * 64;

  if (isQ) {
#pragma unroll
    for (int i = 0; i < 8; ++i) {
      int gr = row0 + wm0 + i * 16 + lq * 4;
#pragma unroll
      for (int j = 0; j < 4; ++j) {
        int gc = col0 + wn0 + j * 16 + lr;
        float bsv = p.bq[gc];
#pragma unroll
        for (int r = 0; r < 4; ++r) {
          float v = acc[i][j][r] + bsv;
          v = v > 0.f ? v + 1.f : __expf(v);
          p.Qf[(size_t)(gr + r) * D_ + gc] = (bf16_t)v;
        }
      }
    }
  } else if (nt < 8) {
#pragma unroll
    for (int i = 0; i < 8; ++i) {
      int gr = row0 + wm0 + i * 16 + lq * 4;
#pragma unroll
      for (int j = 0; j < 4; ++j) {
        int gc = col0 + wn0 + j * 16 + lr;
        float bsv = p.bk[gc];
#pragma unroll
        for (int r = 0; r < 4; ++r) {
          float v = acc[i][j][r] + bsv;
          v = v > 0.f ? v + 1.f : __expf(v);
          p.Kf[(size_t)(gr + r) * D_ + gc] = (bf16_t)v;
        }
      }
    }
  } else {
#pragma unroll
    for (int i = 0; i < 8; ++i) {
      int gr = row0 + wm0 + i * 16 + lq * 4;
#pragma unroll
      for (int j = 0; j < 4; ++j) {
        int gc = col0 + wn0 + j * 16 + lr;     // 1024..2047
        int vc = gc - 1024;
        float bsv = p.bv[vc];
#pragma unroll
        for (int r = 0; r < 4; ++r) {
          float v = acc[i][j][r] + bsv;
          p.Vf[(size_t)(gr + r) * D_ + vc] = (bf16_t)v;
        }
      }
    }
  }
}

// ---------------- output GEMM (256^2 tiles): out = X*WoT + bo (fp32 out) ----------------
__global__ __launch_bounds__(512, 2) void gemm_out256_kernel(
    const bf16_t* __restrict__ A,    // M x K
    const bf16_t* __restrict__ Bt,   // N x K
    const float* __restrict__ bias,
    float* __restrict__ outf) {
  __shared__ __attribute__((aligned(16))) bf16_t As[4 * 8192];
  __shared__ __attribute__((aligned(16))) bf16_t Bs[4 * 8192];
  const unsigned L = blockIdx.x;       // 0..255
  const unsigned xcd = L & 7;
  const unsigned slot = L >> 3;        // 0..31
  const unsigned mq = slot >> 3;       // 0..3
  const unsigned s8 = slot & 7;
  const int mt = xcd * 8 + mq * 2 + (s8 & 1);
  const int nt = s8 >> 1;              // 0..3
  const int row0 = mt * 256;
  const int col0 = nt * 256;

  floatx4 acc[8][4];
#pragma unroll
  for (int i = 0; i < 8; ++i)
#pragma unroll
    for (int j = 0; j < 4; ++j) acc[i][j] = (floatx4){0.f, 0.f, 0.f, 0.f};

  gemm256_core(A, Bt, row0, col0, As, Bs, acc);

  const int tid = threadIdx.x;
  const int w = tid >> 6;
  const int lane = tid & 63;
  const int lr = lane & 15;
  const int lq = lane >> 4;
  const int wm0 = (w >> 2) * 128;
  const int wn0 = (w & 3) * 64;

#pragma unroll
  for (int i = 0; i < 8; ++i) {
    int gr = row0 + wm0 + i * 16 + lq * 4;
#pragma unroll
    for (int j = 0; j < 4; ++j) {
      int gc = col0 + wn0 + j * 16 + lr;
      float bsv = bias[gc];
#pragma unroll
      for (int r = 0; r < 4; ++r)
        outf[(size_t)(gr + r) * D_ + gc] = acc[i][j][r] + bsv;
    }
  }
}

// ---------------- KV summarize (MFMA) -> per-(bh,sc) partials, no atomics ----------------
#define KVP 68  // LDS row stride (elems) for transposed tiles
__global__ __launch_bounds__(256) void kv_mfma_kernel(
    const bf16_t* __restrict__ Kf, const bf16_t* __restrict__ Vf,
    float* __restrict__ KVpart, float* __restrict__ Kspart) {
  __shared__ __attribute__((aligned(16))) bf16_t Kt[64 * KVP];  // [d][s]
  __shared__ __attribute__((aligned(16))) bf16_t Vt[64 * KVP];  // [e][s]
  const int t = threadIdx.x;
  const int w = t >> 6, lane = t & 63;
  const int lr = lane & 15, lq = lane >> 4;
  const int bh = blockIdx.x, sc = blockIdx.y;
  const int b = bh >> 4, h = bh & 15;
  const size_t base = (size_t)b * S_ * D_ + (size_t)h * HD_;
  const int p = t >> 3;          // row-pair 0..31
  const int c0 = (t & 7) * 8;    // feature col 0..56

  floatx4 acc[4], accn[4];
#pragma unroll
  for (int j = 0; j < 4; ++j) {
    acc[j] = (floatx4){0.f, 0.f, 0.f, 0.f};
    accn[j] = (floatx4){0.f, 0.f, 0.f, 0.f};
  }
  bf16x8 ones;
#pragma unroll
  for (int u = 0; u < 8; ++u) ones[u] = (bf16_t)(lr == 0 ? 1.f : 0.f);

  for (int st = 0; st < 8; ++st) {  // 8 tiles x 64 s = 512 s
    int s0 = sc * 512 + st * 64;
    bf16x8 ka = *(const bf16x8*)&Kf[base + (size_t)(s0 + 2 * p) * D_ + c0];
    bf16x8 kb = *(const bf16x8*)&Kf[base + (size_t)(s0 + 2 * p + 1) * D_ + c0];
    bf16x8 va = *(const bf16x8*)&Vf[base + (size_t)(s0 + 2 * p) * D_ + c0];
    bf16x8 vb = *(const bf16x8*)&Vf[base + (size_t)(s0 + 2 * p + 1) * D_ + c0];
    __syncthreads();  // previous iter's reads done before overwriting LDS
#pragma unroll
    for (int u = 0; u < 8; ++u) {
      *(bf16x2*)&Kt[(c0 + u) * KVP + 2 * p] = (bf16x2){ka[u], kb[u]};
      *(bf16x2*)&Vt[(c0 + u) * KVP + 2 * p] = (bf16x2){va[u], vb[u]};
    }
    __syncthreads();
#pragma unroll
    for (int ks = 0; ks < 2; ++ks) {
      bf16x8 af = *(const bf16x8*)&Vt[(w * 16 + lr) * KVP + ks * 32 + lq * 8];
      bf16x8 bf_[4];
#pragma unroll
      for (int j = 0; j < 4; ++j)
        bf_[j] = *(const bf16x8*)&Kt[(j * 16 + lr) * KVP + ks * 32 + lq * 8];
#pragma unroll
      for (int j = 0; j < 4; ++j)
        acc[j] = __builtin_amdgcn_mfma_f32_16x16x32_bf16(af, bf_[j], acc[j], 0, 0, 0);
      if (w == 0) {
#pragma unroll
        for (int j = 0; j < 4; ++j)
          accn[j] = __builtin_amdgcn_mfma_f32_16x16x32_bf16(ones, bf_[j], accn[j], 0, 0, 0);
      }
    }
  }
  float* kvp = KVpart + ((size_t)bh * 8 + sc) * 4096;
#pragma unroll
  for (int j = 0; j < 4; ++j)
#pragma unroll
    for (int r = 0; r < 4; ++r)
      kvp[(w * 16 + lq * 4 + r) * 64 + j * 16 + lr] = acc[j][r];
  if (w == 0 && lq == 0) {
#pragma unroll
    for (int j = 0; j < 4; ++j)
      Kspart[((size_t)bh * 8 + sc) * 64 + j * 16 + lr] = accn[j][0];
  }
}

// ---------------- reduce partials: KVtg[bh][e][d] = sum_sc, Ksumg likewise ----------------
__global__ __launch_bounds__(256) void kv_reduce_kernel(
    const float* __restrict__ KVpart, const float* __restrict__ Kspart,
    float* __restrict__ KVtg, float* __restrict__ Ksumg) {
  const int bid = blockIdx.x;
  const int t = threadIdx.x;
  if (bid < 256) {
    int idx4 = bid * 256 + t;        // 0..65535
    int bh = idx4 >> 10;
    int d4 = idx4 & 1023;
    float4 s = {0.f, 0.f, 0.f, 0.f};
#pragma unroll
    for (int sc = 0; sc < 8; ++sc) {
      float4 v = *(const float4*)&KVpart[((size_t)bh * 8 + sc) * 4096 + d4 * 4];
      s.x += v.x; s.y += v.y; s.z += v.z; s.w += v.w;
    }
    *(float4*)&KVtg[(size_t)bh * 4096 + d4 * 4] = s;
  } else {
    int idx = (bid - 256) * 256 + t;  // 0..1023
    int bh = idx >> 4;
    int d4 = idx & 15;
    float4 s = {0.f, 0.f, 0.f, 0.f};
#pragma unroll
    for (int sc = 0; sc < 8; ++sc) {
      float4 v = *(const float4*)&Kspart[((size_t)bh * 8 + sc) * 64 + d4 * 4];
      s.x += v.x; s.y += v.y; s.z += v.z; s.w += v.w;
    }
    *(float4*)&Ksumg[bh * 64 + d4 * 4] = s;
  }
}

// ---------------- attend (MFMA): X[b,q,h,:] = (Q . KV) / (Q . Ksum + 1e-6) ----------------
__global__ __launch_bounds__(256) void attend_mfma_kernel(
    const bf16_t* __restrict__ Qf, const float* __restrict__ KVtg,
    const float* __restrict__ Ksumg, bf16_t* __restrict__ X) {
  __shared__ __attribute__((aligned(16))) bf16_t As[256 * 64];  // 32KB
  __shared__ __attribute__((aligned(16))) bf16_t Bs[64 * 64];   // 8KB
  const int t = threadIdx.x;
  const int w = t >> 6;
  const int lane = t & 63;
  const int lr = lane & 15;
  const int lq = lane >> 4;
  const int rx = lr & 7;
  const int bh = blockIdx.y;
  const int b = bh >> 4, h = bh & 15;
  const int q0 = blockIdx.x * 256;
  const size_t qbase = ((size_t)b * S_ + q0) * D_ + (size_t)h * HD_;

  // stage Q rows via async LDS DMA (swizzled source chunk)
  {
    const int r8 = lane >> 3;
    const int cs = (((lane & 7) ^ (r8 & 7)) << 3);
#pragma unroll
    for (int it = 0; it < 8; ++it) {
      int r = w * 64 + it * 8 + r8;
      async_load16(&Qf[qbase + (size_t)r * D_ + cs], &As[(w * 64 + it * 8) * 64]);
    }
  }
  // stage KV^T: fp32 -> bf16 cast, swizzled store
  {
    const float* src = KVtg + (size_t)bh * 4096;
    int i0 = t * 16;
    float4 f0 = *(const float4*)(src + i0);
    float4 f1 = *(const float4*)(src + i0 + 4);
    float4 f2 = *(const float4*)(src + i0 + 8);
    float4 f3 = *(const float4*)(src + i0 + 12);
    bf16x8 o1, o2;
    o1[0] = (bf16_t)f0.x; o1[1] = (bf16_t)f0.y; o1[2] = (bf16_t)f0.z; o1[3] = (bf16_t)f0.w;
    o1[4] = (bf16_t)f1.x; o1[5] = (bf16_t)f1.y; o1[6] = (bf16_t)f1.z; o1[7] = (bf16_t)f1.w;
    o2[0] = (bf16_t)f2.x; o2[1] = (bf16_t)f2.y; o2[2] = (bf16_t)f2.z; o2[3] = (bf16_t)f2.w;
    o2[4] = (bf16_t)f3.x; o2[5] = (bf16_t)f3.y; o2[6] = (bf16_t)f3.z; o2[7] = (bf16_t)f3.w;
    int r = t >> 2;
    int cc = (t & 3) * 2;
    int rxw = r & 7;
    *(bf16x8*)&Bs[r * 64 + ((cc ^ rxw) << 3)] = o1;
    *(bf16x8*)&Bs[r * 64 + (((cc + 1) ^ rxw) << 3)] = o2;
  }

  // norm B fragments: row n=0 holds Ksum (bf16), rows 1..15 zero
  bf16x8 bn[2];
#pragma unroll
  for (int ks = 0; ks < 2; ++ks) {
    bf16x8 z;
#pragma unroll
    for (int u = 0; u < 8; ++u) z[u] = (bf16_t)0.f;
    if (lr == 0) {
      const float* kp = &Ksumg[bh * 64 + ks * 32 + lq * 8];
      float4 k1 = *(const float4*)kp;
      float4 k2 = *(const float4*)(kp + 4);
      z[0] = (bf16_t)k1.x; z[1] = (bf16_t)k1.y; z[2] = (bf16_t)k1.z; z[3] = (bf16_t)k1.w;
      z[4] = (bf16_t)k2.x; z[5] = (bf16_t)k2.y; z[6] = (bf16_t)k2.z; z[7] = (bf16_t)k2.w;
    }
    bn[ks] = z;
  }

  floatx4 acc[4][4];
  floatx4 accn[4];
#pragma unroll
  for (int i = 0; i < 4; ++i) {
    accn[i] = (floatx4){0.f, 0.f, 0.f, 0.f};
#pragma unroll
    for (int j = 0; j < 4; ++j) acc[i][j] = (floatx4){0.f, 0.f, 0.f, 0.f};
  }

  __syncthreads();

#pragma unroll
  for (int ks = 0; ks < 2; ++ks) {
    const int go = ((lq + ks * 4) ^ rx) << 3;
    bf16x8 af[4], bfr[4];
#pragma unroll
    for (int i = 0; i < 4; ++i)
      af[i] = *(const bf16x8*)&As[(w * 64 + i * 16 + lr) * 64 + go];
#pragma unroll
    for (int j = 0; j < 4; ++j)
      bfr[j] = *(const bf16x8*)&Bs[(j * 16 + lr) * 64 + go];
#pragma unroll
    for (int i = 0; i < 4; ++i) {
#pragma unroll
      for (int j = 0; j < 4; ++j)
        acc[i][j] = __builtin_amdgcn_mfma_f32_16x16x32_bf16(af[i], bfr[j], acc[i][j], 0, 0, 0);
      accn[i] = __builtin_amdgcn_mfma_f32_16x16x32_bf16(af[i], bn[ks], accn[i], 0, 0, 0);
    }
  }

  // epilogue: normalize and store bf16
#pragma unroll
  for (int i = 0; i < 4; ++i) {
    int rowb = q0 + w * 64 + i * 16 + lq * 4;
#pragma unroll
    for (int r = 0; r < 4; ++r) {
      float nr = __shfl(accn[i][r], lane & 48);
      float inv = 1.f / (nr + 1e-6f);
      size_t rb = ((size_t)b * S_ + rowb + r) * D_ + (size_t)h * HD_;
#pragma unroll
      for (int j = 0; j < 4; ++j)
        X[rb + j * 16 + lr] = (bf16_t)(acc[i][j][r] * inv);
    }
  }
}

extern "C" void kernel_launch(void* const* d_in, const int* in_sizes, int n_in,
                              void* d_out, int out_size, void* d_ws, size_t ws_size,
                              hipStream_t stream) {
  const float* query     = (const float*)d_in[0];
  const float* key_value = (const float*)d_in[1];
  const float* Wq = (const float*)d_in[2];
  const float* bq = (const float*)d_in[3];
  const float* Wk = (const float*)d_in[4];
  const float* bk = (const float*)d_in[5];
  const float* Wv = (const float*)d_in[6];
  const float* bv = (const float*)d_in[7];
  const float* Wo = (const float*)d_in[8];
  const float* bo = (const float*)d_in[9];
  float* out = (float*)d_out;

  char* ws = (char*)d_ws;
  const size_t MB = 1024 * 1024;
  bf16_t* Aq   = (bf16_t*)(ws + 0);         // 32MB (query bf16; later reused as X)
  bf16_t* Akv  = (bf16_t*)(ws + 32 * MB);   // 32MB (key_value bf16; dead after proj)
  float*  KVpart = (float*)(ws + 32 * MB);  // 8MB  (aliases Akv, used after proj)
  float*  Kspart = (float*)(ws + 40 * MB);  // 128KB
  bf16_t* WqT  = (bf16_t*)(ws + 64 * MB);   // 2MB each
  bf16_t* WkT  = (bf16_t*)(ws + 66 * MB);   // WkT and WvT adjacent -> fused N=2048 B matrix
  bf16_t* WvT  = (bf16_t*)(ws + 68 * MB);
  bf16_t* WoT  = (bf16_t*)(ws + 70 * MB);
  bf16_t* Qf   = (bf16_t*)(ws + 72 * MB);   // 32MB
  bf16_t* Kf   = (bf16_t*)(ws + 104 * MB);  // 32MB
  bf16_t* Vf   = (bf16_t*)(ws + 136 * MB);  // 32MB
  float*  KVtg = (float*)(ws + 168 * MB);   // 1MB  (64 x [e][d] fp32)
  float*  Ksumg= (float*)(ws + 169 * MB);   // 16KB

  // 1) prep: casts + transposes
  PrepArgs pa = {query, key_value, Aq, Akv, Wq, Wk, Wv, Wo, WqT, WkT, WvT, WoT};
  prep_kernel<<<20480, 256, 0, stream>>>(pa);

  // 2) merged Q/K/V projection GEMM (256^2 pipelined)
  ProjArgs pj = {Aq, Akv, WqT, WkT, bq, bk, bv, Qf, Kf, Vf};
  proj256_kernel<<<768, 512, 0, stream>>>(pj);

  // 3) KV summarize -> partials
  dim3 kvgrid(64, 8);
  kv_mfma_kernel<<<kvgrid, 256, 0, stream>>>(Kf, Vf, KVpart, Kspart);

  // 4) reduce partials
  kv_reduce_kernel<<<260, 256, 0, stream>>>(KVpart, Kspart, KVtg, Ksumg);

  // 5) attend
  dim3 agrid(S_ / 256, 64);  // (16, 64)
  attend_mfma_kernel<<<agrid, 256, 0, stream>>>(Qf, KVtg, Ksumg, Aq /* X */);

  // 6) output projection (256^2 pipelined)
  gemm_out256_kernel<<<256, 512, 0, stream>>>(Aq, WoT, bo, out);
}